// Round 9
// baseline (181.741 us; speedup 1.0000x reference)
//
#include <hip/hip_runtime.h>
#include <hip/hip_bf16.h>

// Causal flash attention fwd, B=2 H=16 S=2048 D=64, fp32 I/O, bf16 MFMA compute.
// R7 vs R6 (96us, VALU 43%, Occ 19.7%, latency-bound at 2 waves/SIMD):
//  (a) 512-thread blocks: 8 waves = 4 q-groups x 2 kv-halves (kv-split online
//      softmax, merged per strip via LDS) -> 16 waves/CU = 4 waves/SIMD.
//  (b) Vt rebuilt as K-style 128B swizzled rows (byte ^= ((d&7)^((d>>3)&7))<<4):
//      V-staging 8-way bank conflict (== the 3.78M counter) -> 2-way free;
//      PV V-reads 16xb64 -> 8xb128 conflict-free.
//  (c) lane-partial l (sum-reduce once per strip, not per tile); T12 cvt_pk P.
// Kept: strip pairing {31-p, p} (uniform 33 tiles), bf16 K/V pre-convert in d_ws,
// reg-prefetch with lgkm-only barrier B, K LDS XOR-swizzle, defer-max (T13).
// MFMA 16x16x32_bf16 layouts per guide §3 (m89-verified).

typedef unsigned int u32;
typedef unsigned short u16;
typedef unsigned long long u64;
typedef __attribute__((ext_vector_type(8))) short short8;
typedef __attribute__((ext_vector_type(4))) float f32x4;

#define DEV static __device__ __forceinline__

constexpr int S_ = 2048, D_ = 64;
constexpr int ELEMS = 2 * 16 * S_ * D_;              // per tensor
constexpr float SCL = 0.125f * 1.44269504089f;       // D^-0.5 * log2(e)
constexpr float MASKV = -1.0e30f;                    // finite mask (no NaN paths)

DEV u16 f2bf(float f) {
  u32 u = __builtin_bit_cast(u32, f);
  u += 0x7fffu + ((u >> 16) & 1u);   // RNE; inputs are finite
  return (u16)(u >> 16);
}
DEV u32 pk2(float lo, float hi) { return (u32)f2bf(lo) | ((u32)f2bf(hi) << 16); }
DEV u64 pk4(float4 v) { return (u64)pk2(v.x, v.y) | ((u64)pk2(v.z, v.w) << 32); }

struct Q4 { u32 w[4]; };
struct P2 { u64 a, b; };

// ---------------- prologue: f32 -> bf16 tensor convert ----------------
__global__ __launch_bounds__(256)
void convbf(const float* __restrict__ src, u16* __restrict__ dst, int n4) {
  int i = blockIdx.x * blockDim.x + threadIdx.x;
  const int stride = gridDim.x * blockDim.x;
  for (; i < n4; i += stride) {
    float4 v = ((const float4*)src)[i];
    ((u64*)dst)[i] = pk4(v);
  }
}

// V swizzle: inject d bits 0-5 into the bank index, 16B-granular (keeps b128 align)
DEV int vswz(int d) { return (((d & 7) ^ ((d >> 3) & 7)) << 4); }

// ---------------- main kernel (bf16 K/V from d_ws) ----------------
__global__ __launch_bounds__(512, 4)
void fattn(const float* __restrict__ Qg, const u16* __restrict__ Kbf,
           const u16* __restrict__ Vbf, float* __restrict__ Og)
{
  __shared__ __align__(16) u16 Kl[64 * 64];        // 8 KiB, swizzled 128B rows
  __shared__ __align__(16) u16 Vt[64 * 64];        // 8 KiB, [d][kv] swizzled 128B rows
  __shared__ __align__(16) u16 Pl[8][16 * 40];     // 10 KiB, per-wave P [16][40]

  const int tid  = threadIdx.x;
  const int wid  = tid >> 6;        // 0..7
  const int lane = tid & 63;
  const int c    = lane & 15;
  const int g    = lane >> 4;
  const int qg   = wid & 3;         // q-group (16 rows each)
  const int h    = wid >> 2;        // kv-half (32 kv each)

  const int n  = blockIdx.x;
  const int bh = n & 31;
  const int p  = n >> 5;            // 0..15; strips {31-p, p} = 33 tiles uniform

  const float* Qb = Qg  + (size_t)bh * S_ * D_;
  const u16*   Kb = Kbf + (size_t)bh * S_ * D_;
  const u16*   Vb = Vbf + (size_t)bh * S_ * D_;
  float*       Ob = Og  + (size_t)bh * S_ * D_;

  char* Kbyte = (char*)Kl;
  char* Vbyte = (char*)Vt;
  char* Pbyte = (char*)Pl + wid * 1280;

  // ---- staging assignment (512 threads) ----
  const int krow = tid >> 3;          // K row 0..63
  const int km16 = (tid & 7) * 16;    // K byte col
  const int p5   = tid >> 4;          // V kv-pair 0..31
  const int d0v  = (tid & 15) * 4;    // V d-quad
  short8 pkA;
  u64 pv0, pv1;

#define ISSUE(T) do {                                                        \
    pkA = *(const short8*)((const char*)Kb + (size_t)(T) * 8192 +            \
                           krow * 128 + km16);                               \
    const u16* Vg_ = Vb + (size_t)(T) * 4096;                                \
    pv0 = *(const u64*)(Vg_ + (2 * p5    ) * 64 + d0v);                      \
    pv1 = *(const u64*)(Vg_ + (2 * p5 + 1) * 64 + d0v);                      \
  } while (0)

  ISSUE(0);

  for (int sp = 0; sp < 2; ++sp) {
    const int qb = (sp == 0) ? (31 - p) : p;
    const int q0 = qb * 64;
    const int ntiles = qb + 1;

    // ---- Q fragments (A operand), scale folded into bf16 conversion ----
    const int qrow = q0 + qg * 16 + c;
    short8 qf[2];
    for (int kc = 0; kc < 2; ++kc) {
      const float* qp = Qb + (size_t)qrow * D_ + kc * 32 + 8 * g;
      float4 x = *(const float4*)qp;
      float4 y = *(const float4*)(qp + 4);
      Q4 q;
      q.w[0] = pk2(x.x * SCL, x.y * SCL);
      q.w[1] = pk2(x.z * SCL, x.w * SCL);
      q.w[2] = pk2(y.x * SCL, y.y * SCL);
      q.w[3] = pk2(y.z * SCL, y.w * SCL);
      qf[kc] = __builtin_bit_cast(short8, q);
    }

    f32x4 oa[4];
    for (int nd = 0; nd < 4; ++nd) oa[nd] = f32x4{0.f, 0.f, 0.f, 0.f};
    float mrow[4], lrow[4];
    for (int i = 0; i < 4; ++i) { mrow[i] = MASKV; lrow[i] = 0.f; }

    for (int t = 0; t < ntiles; ++t) {
      const int kv0 = t * 64;
      __syncthreads();   // barrier A: full drain; prev tile reads + merge done

      // ---- write prefetched tile -> LDS (K and V both swizzled 128B rows) ----
      {
        *(short8*)(Kbyte + krow * 128 + (km16 ^ ((krow & 7) << 4))) = pkA;
        const u32 lo0 = (u32)pv0, hi0 = (u32)(pv0 >> 32);
        const u32 lo1 = (u32)pv1, hi1 = (u32)(pv1 >> 32);
        const int cb = 4 * p5;
        int d = d0v;
        *(u32*)(Vbyte + d * 128 + (cb ^ vswz(d))) = (lo0 & 0xffffu) | (lo1 << 16); ++d;
        *(u32*)(Vbyte + d * 128 + (cb ^ vswz(d))) = (lo0 >> 16) | (lo1 & 0xffff0000u); ++d;
        *(u32*)(Vbyte + d * 128 + (cb ^ vswz(d))) = (hi0 & 0xffffu) | (hi1 << 16); ++d;
        *(u32*)(Vbyte + d * 128 + (cb ^ vswz(d))) = (hi0 >> 16) | (hi1 & 0xffff0000u);
      }

      // ---- issue next tile's loads (cross-strip tile 0 at boundary) ----
      if (t + 1 < ntiles) ISSUE(t + 1);
      else if (sp == 0)   ISSUE(0);

      // barrier B: drain LDS writes only — NOT vmcnt (keep prefetch in flight)
      asm volatile("s_waitcnt lgkmcnt(0)" ::: "memory");
      __builtin_amdgcn_s_barrier();
      asm volatile("" ::: "memory");

      // ---- QK^T: this wave's 16q x 32kv half ----
      f32x4 sa[2];
      for (int nn = 0; nn < 2; ++nn) {
        sa[nn] = f32x4{0.f, 0.f, 0.f, 0.f};
        const int rowk = 32 * h + 16 * nn + c;
        const int base = rowk * 128;
        const int swz  = (rowk & 7) << 4;
        for (int kc = 0; kc < 2; ++kc) {
          short8 kf = *(const short8*)(Kbyte + base + ((kc * 64 + 16 * g) ^ swz));
          sa[nn] = __builtin_amdgcn_mfma_f32_16x16x32_bf16(qf[kc], kf, sa[nn], 0, 0, 0);
        }
      }

      // ---- mask + online softmax (log2 domain), defer-max, lane-partial l ----
      const bool diag = (t == ntiles - 1);
      for (int i = 0; i < 4; ++i) {
        const int qabs = q0 + qg * 16 + 4 * g + i;
        float s0v = sa[0][i], s1v = sa[1][i];
        if (diag) {
          const int kvb = kv0 + 32 * h;
          if (kvb +  0 + c > qabs) s0v = MASKV;
          if (kvb + 16 + c > qabs) s1v = MASKV;
        }
        float mx = fmaxf(s0v, s1v);
        mx = fmaxf(mx, __shfl_xor(mx, 1));
        mx = fmaxf(mx, __shfl_xor(mx, 2));
        mx = fmaxf(mx, __shfl_xor(mx, 4));
        mx = fmaxf(mx, __shfl_xor(mx, 8));
        if (!__all(mx <= mrow[i] + 8.0f)) {
          const float nm = fmaxf(mrow[i], mx);
          const float al = exp2f(mrow[i] - nm);
          mrow[i] = nm;
          lrow[i] *= al;
          oa[0][i] *= al; oa[1][i] *= al; oa[2][i] *= al; oa[3][i] *= al;
        }
        const float m_ = mrow[i];
        const float p0 = exp2f(s0v - m_);
        const float p1 = exp2f(s1v - m_);
        lrow[i] += p0 + p1;                        // lane-partial; reduced at strip end
        u32 pk;
        asm("v_cvt_pk_bf16_f32 %0, %1, %2" : "=v"(pk) : "v"(p0), "v"(p1));
        char* pr = Pbyte + (4 * g + i) * 80;
        *(u16*)(pr + 2 * c)      = (u16)pk;        // kv-local col c
        *(u16*)(pr + 32 + 2 * c) = (u16)(pk >> 16);// kv-local col 16+c
      }

      // ---- PV: O += P(16x32) @ V(32x64), V from swizzled Vt ----
      {
        short8 af = *(const short8*)(Pbyte + c * 80 + 16 * g);
        for (int nd = 0; nd < 4; ++nd) {
          const int d = nd * 16 + c;
          short8 vf = *(const short8*)(Vbyte + d * 128 + ((64 * h + 16 * g) ^ vswz(d)));
          oa[nd] = __builtin_amdgcn_mfma_f32_16x16x32_bf16(af, vf, oa[nd], 0, 0, 0);
        }
      }
    }

    // ---- strip epilogue: reduce l across 16 lanes, merge kv-halves, store ----
    for (int i = 0; i < 4; ++i) {
      float ls = lrow[i];
      ls += __shfl_xor(ls, 1);
      ls += __shfl_xor(ls, 2);
      ls += __shfl_xor(ls, 4);
      ls += __shfl_xor(ls, 8);
      lrow[i] = ls;
    }
    __syncthreads();   // all waves done with Kl/Vt/P tile reads
    // merge buffers: O1 per q-group (4KB) in Kl (qg 0,1) / Vt (qg 2,3);
    // m1,l1 in the h=1 wave's own P area (first 128B).
    float* ob = (qg < 2) ? ((float*)Kl + qg * 1024) : ((float*)Vt + (qg - 2) * 1024);
    if (h == 1) {
      float* mb = (float*)Pbyte;
      if (c == 0) {
        for (int i = 0; i < 4; ++i) {
          mb[4 * g + i]      = mrow[i];
          mb[16 + 4 * g + i] = lrow[i];
        }
      }
      for (int i = 0; i < 4; ++i)
        for (int nd = 0; nd < 4; ++nd)
          ob[(4 * g + i) * 64 + ((nd * 16 + c) ^ (g << 4))] = oa[nd][i];
    }
    __syncthreads();
    if (h == 0) {
      const float* mb1 = (const float*)((char*)Pl + (4 + qg) * 1280);
      for (int i = 0; i < 4; ++i) {
        const float m1 = mb1[4 * g + i];
        const float l1 = mb1[16 + 4 * g + i];
        const float m  = fmaxf(mrow[i], m1);
        const float a0 = exp2f(mrow[i] - m);
        const float a1 = exp2f(m1 - m);
        const float rl = 1.0f / (lrow[i] * a0 + l1 * a1);
        float* op = Ob + (size_t)(q0 + qg * 16 + 4 * g + i) * D_;
        for (int nd = 0; nd < 4; ++nd) {
          const float o1 = ob[(4 * g + i) * 64 + ((nd * 16 + c) ^ (g << 4))];
          op[nd * 16 + c] = (oa[nd][i] * a0 + o1 * a1) * rl;
        }
      }
    }
  }
}

// ---------------- fallback (f32 K/V, R4 form) — only if ws too small ----------
__global__ __launch_bounds__(256, 4)
void fattn_fb(const float* __restrict__ Qg, const float* __restrict__ Kg,
              const float* __restrict__ Vg, float* __restrict__ Og)
{
  __shared__ __align__(16) u16 Kl[64 * 64];
  __shared__ __align__(16) u16 Vt[64 * 68];
  __shared__ __align__(16) u16 Pl[4][16 * 72];

  const int tid  = threadIdx.x;
  const int wid  = tid >> 6;
  const int lane = tid & 63;
  const int c    = lane & 15;
  const int g    = lane >> 4;

  const int n  = blockIdx.x;
  const int j  = n & 255, kq = n >> 8;
  const int b5 = j & 31,  r3 = j >> 5;
  const int bh = kq * 8 + r3;
  int qb;
  switch (kq) {
    case 0:  qb = b5;              break;
    case 1:  qb = 31 - b5;         break;
    case 2:  qb = (b5 + 16) & 31;  break;
    default: qb = (15 - b5) & 31;  break;
  }
  const int q0 = qb * 64;
  const int ntiles = qb + 1;

  const float* Qb = Qg + (size_t)bh * S_ * D_;
  const float* Kb = Kg + (size_t)bh * S_ * D_;
  const float* Vb = Vg + (size_t)bh * S_ * D_;
  float*       Ob = Og + (size_t)bh * S_ * D_;

  char* Kbyte = (char*)Kl;
  char* Vbyte = (char*)Vt;
  char* Pbyte = (char*)(Pl[wid]);

  const int qrow = q0 + wid * 16 + c;
  short8 qf[2];
  for (int kc = 0; kc < 2; ++kc) {
    const float* qp = Qb + (size_t)qrow * D_ + kc * 32 + 8 * g;
    float4 x = *(const float4*)qp;
    float4 y = *(const float4*)(qp + 4);
    Q4 q;
    q.w[0] = pk2(x.x * SCL, x.y * SCL);
    q.w[1] = pk2(x.z * SCL, x.w * SCL);
    q.w[2] = pk2(y.x * SCL, y.y * SCL);
    q.w[3] = pk2(y.z * SCL, y.w * SCL);
    qf[kc] = __builtin_bit_cast(short8, q);
  }

  f32x4 oa[4];
  for (int nd = 0; nd < 4; ++nd) oa[nd] = f32x4{0.f, 0.f, 0.f, 0.f};
  float mrow[4], lrow[4];
  for (int i = 0; i < 4; ++i) { mrow[i] = -__builtin_inff(); lrow[i] = 0.f; }

  const int cf4  = tid & 15;
  const int krow = tid >> 4;
  const int d0   = cf4 * 4;
  float4 pk0, pk1, pk2v, pk3, pa0, pb0, pa1, pb1;

#define ISSUEF(T) do {                                                    \
    const float* Kt_ = Kb + (size_t)(T) * 64 * D_;                        \
    const float* Vg_ = Vb + (size_t)(T) * 64 * D_;                        \
    pk0 = *(const float4*)(Kt_ + (size_t)(krow     ) * D_ + d0);          \
    pk1 = *(const float4*)(Kt_ + (size_t)(krow + 16) * D_ + d0);          \
    pk2v = *(const float4*)(Kt_ + (size_t)(krow + 32) * D_ + d0);         \
    pk3 = *(const float4*)(Kt_ + (size_t)(krow + 48) * D_ + d0);          \
    const float* s0_ = Vg_ + (size_t)(2 * krow     ) * D_ + d0;           \
    const float* s1_ = Vg_ + (size_t)(2 * krow + 32) * D_ + d0;           \
    pa0 = *(const float4*)s0_;  pb0 = *(const float4*)(s0_ + D_);         \
    pa1 = *(const float4*)s1_;  pb1 = *(const float4*)(s1_ + D_);         \
  } while (0)

  ISSUEF(0);

  for (int t = 0; t < ntiles; ++t) {
    const int kv0 = t * 64;
    __syncthreads();
    {
      const int r0 = krow, r1 = krow + 16, r2 = krow + 32, r3r = krow + 48;
      *(u64*)(Kbyte + r0  * 128 + ((cf4 * 8) ^ ((r0  & 7) << 4))) = pk4(pk0);
      *(u64*)(Kbyte + r1  * 128 + ((cf4 * 8) ^ ((r1  & 7) << 4))) = pk4(pk1);
      *(u64*)(Kbyte + r2  * 128 + ((cf4 * 8) ^ ((r2  & 7) << 4))) = pk4(pk2v);
      *(u64*)(Kbyte + r3r * 128 + ((cf4 * 8) ^ ((r3r & 7) << 4))) = pk4(pk3);
      const int kvl0 = 2 * krow, kvl1 = 2 * krow + 32;
      *(u32*)(Vbyte + (d0 + 0) * 136 + kvl0 * 2) = pk2(pa0.x, pb0.x);
      *(u32*)(Vbyte + (d0 + 1) * 136 + kvl0 * 2) = pk2(pa0.y, pb0.y);
      *(u32*)(Vbyte + (d0 + 2) * 136 + kvl0 * 2) = pk2(pa0.z, pb0.z);
      *(u32*)(Vbyte + (d0 + 3) * 136 + kvl0 * 2) = pk2(pa0.w, pb0.w);
      *(u32*)(Vbyte + (d0 + 0) * 136 + kvl1 * 2) = pk2(pa1.x, pb1.x);
      *(u32*)(Vbyte + (d0 + 1) * 136 + kvl1 * 2) = pk2(pa1.y, pb1.y);
      *(u32*)(Vbyte + (d0 + 2) * 136 + kvl1 * 2) = pk2(pa1.z, pb1.z);
      *(u32*)(Vbyte + (d0 + 3) * 136 + kvl1 * 2) = pk2(pa1.w, pb1.w);
    }
    if (t + 1 < ntiles) ISSUEF(t + 1);
    asm volatile("s_waitcnt lgkmcnt(0)" ::: "memory");
    __builtin_amdgcn_s_barrier();
    asm volatile("" ::: "memory");

    f32x4 sa[4];
    for (int nn = 0; nn < 4; ++nn) {
      sa[nn] = f32x4{0.f, 0.f, 0.f, 0.f};
      const int rowk = nn * 16 + c;
      const int base = rowk * 128;
      const int swz  = (rowk & 7) << 4;
      for (int kc = 0; kc < 2; ++kc) {
        short8 kf = *(const short8*)(Kbyte + base + ((kc * 64 + 16 * g) ^ swz));
        sa[nn] = __builtin_amdgcn_mfma_f32_16x16x32_bf16(qf[kc], kf, sa[nn], 0, 0, 0);
      }
    }

    const bool diag = (t == ntiles - 1);
    float pp[4][4];
    for (int i = 0; i < 4; ++i) {
      const int qg_ = q0 + wid * 16 + 4 * g + i;
      float s0v = sa[0][i], s1v = sa[1][i], s2v = sa[2][i], s3v = sa[3][i];
      if (diag) {
        if (kv0 +  0 + c > qg_) s0v = -__builtin_inff();
        if (kv0 + 16 + c > qg_) s1v = -__builtin_inff();
        if (kv0 + 32 + c > qg_) s2v = -__builtin_inff();
        if (kv0 + 48 + c > qg_) s3v = -__builtin_inff();
      }
      float mx = fmaxf(fmaxf(s0v, s1v), fmaxf(s2v, s3v));
      mx = fmaxf(mx, __shfl_xor(mx, 1));
      mx = fmaxf(mx, __shfl_xor(mx, 2));
      mx = fmaxf(mx, __shfl_xor(mx, 4));
      mx = fmaxf(mx, __shfl_xor(mx, 8));
      const float nm = fmaxf(mrow[i], mx);
      const float al = exp2f(mrow[i] - nm);
      mrow[i] = nm;
      float p0 = exp2f(s0v - nm), p1 = exp2f(s1v - nm);
      float p2 = exp2f(s2v - nm), p3 = exp2f(s3v - nm);
      pp[0][i] = p0; pp[1][i] = p1; pp[2][i] = p2; pp[3][i] = p3;
      float ls = p0 + p1 + p2 + p3;
      ls += __shfl_xor(ls, 1);
      ls += __shfl_xor(ls, 2);
      ls += __shfl_xor(ls, 4);
      ls += __shfl_xor(ls, 8);
      lrow[i] = lrow[i] * al + ls;
      oa[0][i] *= al; oa[1][i] *= al; oa[2][i] *= al; oa[3][i] *= al;
    }

    for (int nn = 0; nn < 4; ++nn)
      for (int i = 0; i < 4; ++i)
        *(u16*)(Pbyte + ((4 * g + i) * 72 + nn * 16 + c) * 2) = f2bf(pp[nn][i]);

    for (int kc = 0; kc < 2; ++kc) {
      short8 af = *(const short8*)(Pbyte + c * 144 + kc * 64 + 16 * g);
      for (int nd = 0; nd < 4; ++nd) {
        const int d = nd * 16 + c;
        P2 pv;
        pv.a = *(const u64*)(Vbyte + d * 136 + kc * 64 + 16 * g);
        pv.b = *(const u64*)(Vbyte + d * 136 + kc * 64 + 16 * g + 8);
        short8 vf = __builtin_bit_cast(short8, pv);
        oa[nd] = __builtin_amdgcn_mfma_f32_16x16x32_bf16(af, vf, oa[nd], 0, 0, 0);
      }
    }
  }

  for (int i = 0; i < 4; ++i) {
    const float rl = 1.f / lrow[i];
    float* op = Ob + (size_t)(q0 + wid * 16 + 4 * g + i) * D_ + c;
    op[0]  = oa[0][i] * rl;
    op[16] = oa[1][i] * rl;
    op[32] = oa[2][i] * rl;
    op[48] = oa[3][i] * rl;
  }
}

extern "C" void kernel_launch(void* const* d_in, const int* in_sizes, int n_in,
                              void* d_out, int out_size, void* d_ws, size_t ws_size,
                              hipStream_t stream) {
  const float* q = (const float*)d_in[0];
  const float* k = (const float*)d_in[1];
  const float* v = (const float*)d_in[2];
  float* o = (float*)d_out;

  const size_t need = (size_t)2 * ELEMS * sizeof(u16);   // Kbf + Vbf
  if (ws_size >= need) {
    u16* kbf = (u16*)d_ws;
    u16* vbf = kbf + ELEMS;
    const int n4 = ELEMS / 4;
    convbf<<<1024, 256, 0, stream>>>(k, kbf, n4);
    convbf<<<1024, 256, 0, stream>>>(v, vbf, n4);
    fattn<<<512, 512, 0, stream>>>(q, kbf, vbf, o);
  } else {
    fattn_fb<<<1024, 256, 0, stream>>>(q, k, v, o);
  }
}

// Round 10
// 152.941 us; speedup vs baseline: 1.1883x; 1.1883x over previous
//
#include <hip/hip_runtime.h>
#include <hip/hip_bf16.h>

// Causal flash attention fwd, B=2 H=16 S=2048 D=64, fp32 I/O, bf16 MFMA compute.
// R10 vs R9 (106us, VALU 47%, Occ 37.5%, DS-pipe-bound):
//  (1) conditional max-reduce: 4-shfl cross-lane max runs ONLY when
//      !__all(lane-local max <= mrow+8) -- steady-state zero shuffles/tile.
//      (P bounded by 2^8; merge at strip end is exact for any consistent m.)
//  (2) kv-permuted P/V layout pi(k)=(k>>1)+16(k&1): P stored as one u32/row
//      (cvt_pk pair at byte 4c); V staged with row-pairs (r, r+16) so Vt
//      carries the same permutation. kv-axis permutation is PV-invariant.
// NOTE: SQ_LDS_BANK_CONFLICT frozen at 3784704 across R3/R4/R6/R9 -> counter
// untrustworthy in this harness; not used as evidence.
// Kept from R9: 8 waves = 4 qg x 2 kv-half split + strip-end merge, strip
// pairing {31-p,p}, bf16 K/V pre-convert (d_ws), reg-prefetch + lgkm-only
// barrier B, K/V 128B-row XOR swizzles, defer-max (T13), cvt_pk (T12).

typedef unsigned int u32;
typedef unsigned short u16;
typedef unsigned long long u64;
typedef __attribute__((ext_vector_type(8))) short short8;
typedef __attribute__((ext_vector_type(4))) float f32x4;

#define DEV static __device__ __forceinline__

constexpr int S_ = 2048, D_ = 64;
constexpr int ELEMS = 2 * 16 * S_ * D_;              // per tensor
constexpr float SCL = 0.125f * 1.44269504089f;       // D^-0.5 * log2(e)
constexpr float MASKV = -1.0e30f;                    // finite mask (no NaN paths)

DEV u16 f2bf(float f) {
  u32 u = __builtin_bit_cast(u32, f);
  u += 0x7fffu + ((u >> 16) & 1u);   // RNE; inputs are finite
  return (u16)(u >> 16);
}
DEV u32 pk2(float lo, float hi) { return (u32)f2bf(lo) | ((u32)f2bf(hi) << 16); }
DEV u64 pk4(float4 v) { return (u64)pk2(v.x, v.y) | ((u64)pk2(v.z, v.w) << 32); }

struct Q4 { u32 w[4]; };
struct P2 { u64 a, b; };

// ---------------- prologue: f32 -> bf16 tensor convert ----------------
__global__ __launch_bounds__(256)
void convbf(const float* __restrict__ src, u16* __restrict__ dst, int n4) {
  int i = blockIdx.x * blockDim.x + threadIdx.x;
  const int stride = gridDim.x * blockDim.x;
  for (; i < n4; i += stride) {
    float4 v = ((const float4*)src)[i];
    ((u64*)dst)[i] = pk4(v);
  }
}

// V swizzle: inject d bits into the bank index, 16B-granular (keeps b128 align)
DEV int vswz(int d) { return (((d & 7) ^ ((d >> 3) & 7)) << 4); }

// ---------------- main kernel (bf16 K/V from d_ws) ----------------
__global__ __launch_bounds__(512, 4)
void fattn(const float* __restrict__ Qg, const u16* __restrict__ Kbf,
           const u16* __restrict__ Vbf, float* __restrict__ Og)
{
  __shared__ __align__(16) u16 Kl[64 * 64];        // 8 KiB, swizzled 128B rows
  __shared__ __align__(16) u16 Vt[64 * 64];        // 8 KiB, [d][k] swizzled, kv-permuted
  __shared__ __align__(16) u16 Pl[8][16 * 40];     // 10 KiB, per-wave P [16][40]

  const int tid  = threadIdx.x;
  const int wid  = tid >> 6;        // 0..7
  const int lane = tid & 63;
  const int c    = lane & 15;
  const int g    = lane >> 4;
  const int qg   = wid & 3;         // q-group (16 rows each)
  const int h    = wid >> 2;        // kv-half (32 kv each)

  const int n  = blockIdx.x;
  const int bh = n & 31;
  const int p  = n >> 5;            // 0..15; strips {31-p, p} = 33 tiles uniform

  const float* Qb = Qg  + (size_t)bh * S_ * D_;
  const u16*   Kb = Kbf + (size_t)bh * S_ * D_;
  const u16*   Vb = Vbf + (size_t)bh * S_ * D_;
  float*       Ob = Og  + (size_t)bh * S_ * D_;

  char* Kbyte = (char*)Kl;
  char* Vbyte = (char*)Vt;
  char* Pbyte = (char*)Pl + wid * 1280;

  // ---- staging assignment (512 threads) ----
  const int krow = tid >> 3;          // K row 0..63
  const int km16 = (tid & 7) * 16;    // K byte col
  const int pi   = tid >> 4;          // V k-pair index 0..31
  const int vlo  = pi + (pi & 16);    // V kv rows (vlo, vlo+16) -> k (2pi, 2pi+1)
  const int d0v  = (tid & 15) * 4;    // V d-quad
  short8 pkA;
  u64 pv0, pv1;

#define ISSUE(T) do {                                                        \
    pkA = *(const short8*)((const char*)Kb + (size_t)(T) * 8192 +            \
                           krow * 128 + km16);                               \
    const u16* Vg_ = Vb + (size_t)(T) * 4096;                                \
    pv0 = *(const u64*)(Vg_ + (size_t)(vlo     ) * 64 + d0v);                \
    pv1 = *(const u64*)(Vg_ + (size_t)(vlo + 16) * 64 + d0v);                \
  } while (0)

  ISSUE(0);

  for (int sp = 0; sp < 2; ++sp) {
    const int qb = (sp == 0) ? (31 - p) : p;
    const int q0 = qb * 64;
    const int ntiles = qb + 1;

    // ---- Q fragments (A operand), scale folded into bf16 conversion ----
    const int qrow = q0 + qg * 16 + c;
    short8 qf[2];
    for (int kc = 0; kc < 2; ++kc) {
      const float* qp = Qb + (size_t)qrow * D_ + kc * 32 + 8 * g;
      float4 x = *(const float4*)qp;
      float4 y = *(const float4*)(qp + 4);
      Q4 q;
      q.w[0] = pk2(x.x * SCL, x.y * SCL);
      q.w[1] = pk2(x.z * SCL, x.w * SCL);
      q.w[2] = pk2(y.x * SCL, y.y * SCL);
      q.w[3] = pk2(y.z * SCL, y.w * SCL);
      qf[kc] = __builtin_bit_cast(short8, q);
    }

    f32x4 oa[4];
    for (int nd = 0; nd < 4; ++nd) oa[nd] = f32x4{0.f, 0.f, 0.f, 0.f};
    float mrow[4], lrow[4];
    for (int i = 0; i < 4; ++i) { mrow[i] = MASKV; lrow[i] = 0.f; }

    for (int t = 0; t < ntiles; ++t) {
      const int kv0 = t * 64;
      __syncthreads();   // barrier A: full drain; prev tile reads + merge done

      // ---- write prefetched tile -> LDS (K and V swizzled 128B rows) ----
      {
        *(short8*)(Kbyte + krow * 128 + (km16 ^ ((krow & 7) << 4))) = pkA;
        const u32 lo0 = (u32)pv0, hi0 = (u32)(pv0 >> 32);
        const u32 lo1 = (u32)pv1, hi1 = (u32)(pv1 >> 32);
        const int cb = 4 * pi;     // u32 covers k-slots (2pi, 2pi+1)
        int d = d0v;
        *(u32*)(Vbyte + d * 128 + (cb ^ vswz(d))) = (lo0 & 0xffffu) | (lo1 << 16); ++d;
        *(u32*)(Vbyte + d * 128 + (cb ^ vswz(d))) = (lo0 >> 16) | (lo1 & 0xffff0000u); ++d;
        *(u32*)(Vbyte + d * 128 + (cb ^ vswz(d))) = (hi0 & 0xffffu) | (hi1 << 16); ++d;
        *(u32*)(Vbyte + d * 128 + (cb ^ vswz(d))) = (hi0 >> 16) | (hi1 & 0xffff0000u);
      }

      // ---- issue next tile's loads (cross-strip tile 0 at boundary) ----
      if (t + 1 < ntiles) ISSUE(t + 1);
      else if (sp == 0)   ISSUE(0);

      // barrier B: drain LDS writes only — NOT vmcnt (keep prefetch in flight)
      asm volatile("s_waitcnt lgkmcnt(0)" ::: "memory");
      __builtin_amdgcn_s_barrier();
      asm volatile("" ::: "memory");

      // ---- QK^T: this wave's 16q x 32kv half ----
      f32x4 sa[2];
      for (int nn = 0; nn < 2; ++nn) {
        sa[nn] = f32x4{0.f, 0.f, 0.f, 0.f};
        const int rowk = 32 * h + 16 * nn + c;
        const int base = rowk * 128;
        const int swz  = (rowk & 7) << 4;
        for (int kc = 0; kc < 2; ++kc) {
          short8 kf = *(const short8*)(Kbyte + base + ((kc * 64 + 16 * g) ^ swz));
          sa[nn] = __builtin_amdgcn_mfma_f32_16x16x32_bf16(qf[kc], kf, sa[nn], 0, 0, 0);
        }
      }

      // ---- mask + online softmax: conditional cross-lane reduce ----
      const bool diag = (t == ntiles - 1);
      for (int i = 0; i < 4; ++i) {
        const int qabs = q0 + qg * 16 + 4 * g + i;
        float s0v = sa[0][i], s1v = sa[1][i];
        if (diag) {
          const int kvb = kv0 + 32 * h;
          if (kvb +  0 + c > qabs) s0v = MASKV;
          if (kvb + 16 + c > qabs) s1v = MASKV;
        }
        const float lmx = fmaxf(s0v, s1v);   // lane-local max only
        // full reduce + rescale ONLY when some lane exceeds mrow+8 (rare):
        if (!__all(lmx <= mrow[i] + 8.0f)) {
          float mx = lmx;
          mx = fmaxf(mx, __shfl_xor(mx, 1));
          mx = fmaxf(mx, __shfl_xor(mx, 2));
          mx = fmaxf(mx, __shfl_xor(mx, 4));
          mx = fmaxf(mx, __shfl_xor(mx, 8));
          const float nm = fmaxf(mrow[i], mx);
          const float al = exp2f(mrow[i] - nm);   // 0 on first finite tile
          mrow[i] = nm;
          lrow[i] *= al;
          oa[0][i] *= al; oa[1][i] *= al; oa[2][i] *= al; oa[3][i] *= al;
        }
        const float m_ = mrow[i];
        const float p0 = exp2f(s0v - m_);    // bounded by 2^8
        const float p1 = exp2f(s1v - m_);
        lrow[i] += p0 + p1;                  // lane-partial; reduced per strip
        u32 pk;
        asm("v_cvt_pk_bf16_f32 %0, %1, %2" : "=v"(pk) : "v"(p0), "v"(p1));
        // one u32 store: k-slots (2c, 2c+1) = kv (c, c+16)  [pi-permutation]
        *(u32*)(Pbyte + (4 * g + i) * 80 + 4 * c) = pk;
      }

      // ---- PV: O += P(16x32) @ V(32x64), both kv-permuted consistently ----
      {
        short8 af = *(const short8*)(Pbyte + c * 80 + 16 * g);
        for (int nd = 0; nd < 4; ++nd) {
          const int d = nd * 16 + c;
          short8 vf = *(const short8*)(Vbyte + d * 128 + ((64 * h + 16 * g) ^ vswz(d)));
          oa[nd] = __builtin_amdgcn_mfma_f32_16x16x32_bf16(af, vf, oa[nd], 0, 0, 0);
        }
      }
    }

    // ---- strip epilogue: reduce l across 16 lanes, merge kv-halves, store ----
    for (int i = 0; i < 4; ++i) {
      float ls = lrow[i];
      ls += __shfl_xor(ls, 1);
      ls += __shfl_xor(ls, 2);
      ls += __shfl_xor(ls, 4);
      ls += __shfl_xor(ls, 8);
      lrow[i] = ls;
    }
    __syncthreads();   // all waves done with Kl/Vt/P tile reads
    // merge buffers: O1 per q-group (4KB) in Kl (qg 0,1) / Vt (qg 2,3);
    // m1,l1 in the h=1 wave's own P area (first 128B).
    float* ob = (qg < 2) ? ((float*)Kl + qg * 1024) : ((float*)Vt + (qg - 2) * 1024);
    if (h == 1) {
      float* mb = (float*)Pbyte;
      if (c == 0) {
        for (int i = 0; i < 4; ++i) {
          mb[4 * g + i]      = mrow[i];
          mb[16 + 4 * g + i] = lrow[i];
        }
      }
      for (int i = 0; i < 4; ++i)
        for (int nd = 0; nd < 4; ++nd)
          ob[(4 * g + i) * 64 + ((nd * 16 + c) ^ (g << 4))] = oa[nd][i];
    }
    __syncthreads();
    if (h == 0) {
      const float* mb1 = (const float*)((char*)Pl + (4 + qg) * 1280);
      for (int i = 0; i < 4; ++i) {
        const float m1 = mb1[4 * g + i];
        const float l1 = mb1[16 + 4 * g + i];
        const float m  = fmaxf(mrow[i], m1);
        const float a0 = exp2f(mrow[i] - m);
        const float a1 = exp2f(m1 - m);
        const float rl = 1.0f / (lrow[i] * a0 + l1 * a1);
        float* op = Ob + (size_t)(q0 + qg * 16 + 4 * g + i) * D_;
        for (int nd = 0; nd < 4; ++nd) {
          const float o1 = ob[(4 * g + i) * 64 + ((nd * 16 + c) ^ (g << 4))];
          op[nd * 16 + c] = (oa[nd][i] * a0 + o1 * a1) * rl;
        }
      }
    }
  }
}

// ---------------- fallback (f32 K/V, R4 form) — only if ws too small ----------
__global__ __launch_bounds__(256, 4)
void fattn_fb(const float* __restrict__ Qg, const float* __restrict__ Kg,
              const float* __restrict__ Vg, float* __restrict__ Og)
{
  __shared__ __align__(16) u16 Kl[64 * 64];
  __shared__ __align__(16) u16 Vt[64 * 68];
  __shared__ __align__(16) u16 Pl[4][16 * 72];

  const int tid  = threadIdx.x;
  const int wid  = tid >> 6;
  const int lane = tid & 63;
  const int c    = lane & 15;
  const int g    = lane >> 4;

  const int n  = blockIdx.x;
  const int j  = n & 255, kq = n >> 8;
  const int b5 = j & 31,  r3 = j >> 5;
  const int bh = kq * 8 + r3;
  int qb;
  switch (kq) {
    case 0:  qb = b5;              break;
    case 1:  qb = 31 - b5;         break;
    case 2:  qb = (b5 + 16) & 31;  break;
    default: qb = (15 - b5) & 31;  break;
  }
  const int q0 = qb * 64;
  const int ntiles = qb + 1;

  const float* Qb = Qg + (size_t)bh * S_ * D_;
  const float* Kb = Kg + (size_t)bh * S_ * D_;
  const float* Vb = Vg + (size_t)bh * S_ * D_;
  float*       Ob = Og + (size_t)bh * S_ * D_;

  char* Kbyte = (char*)Kl;
  char* Vbyte = (char*)Vt;
  char* Pbyte = (char*)(Pl[wid]);

  const int qrow = q0 + wid * 16 + c;
  short8 qf[2];
  for (int kc = 0; kc < 2; ++kc) {
    const float* qp = Qb + (size_t)qrow * D_ + kc * 32 + 8 * g;
    float4 x = *(const float4*)qp;
    float4 y = *(const float4*)(qp + 4);
    Q4 q;
    q.w[0] = pk2(x.x * SCL, x.y * SCL);
    q.w[1] = pk2(x.z * SCL, x.w * SCL);
    q.w[2] = pk2(y.x * SCL, y.y * SCL);
    q.w[3] = pk2(y.z * SCL, y.w * SCL);
    qf[kc] = __builtin_bit_cast(short8, q);
  }

  f32x4 oa[4];
  for (int nd = 0; nd < 4; ++nd) oa[nd] = f32x4{0.f, 0.f, 0.f, 0.f};
  float mrow[4], lrow[4];
  for (int i = 0; i < 4; ++i) { mrow[i] = -__builtin_inff(); lrow[i] = 0.f; }

  const int cf4  = tid & 15;
  const int krow = tid >> 4;
  const int d0   = cf4 * 4;
  float4 pk0, pk1, pk2v, pk3, pa0, pb0, pa1, pb1;

#define ISSUEF(T) do {                                                    \
    const float* Kt_ = Kb + (size_t)(T) * 64 * D_;                        \
    const float* Vg_ = Vb + (size_t)(T) * 64 * D_;                        \
    pk0 = *(const float4*)(Kt_ + (size_t)(krow     ) * D_ + d0);          \
    pk1 = *(const float4*)(Kt_ + (size_t)(krow + 16) * D_ + d0);          \
    pk2v = *(const float4*)(Kt_ + (size_t)(krow + 32) * D_ + d0);         \
    pk3 = *(const float4*)(Kt_ + (size_t)(krow + 48) * D_ + d0);          \
    const float* s0_ = Vg_ + (size_t)(2 * krow     ) * D_ + d0;           \
    const float* s1_ = Vg_ + (size_t)(2 * krow + 32) * D_ + d0;           \
    pa0 = *(const float4*)s0_;  pb0 = *(const float4*)(s0_ + D_);         \
    pa1 = *(const float4*)s1_;  pb1 = *(const float4*)(s1_ + D_);         \
  } while (0)

  ISSUEF(0);

  for (int t = 0; t < ntiles; ++t) {
    const int kv0 = t * 64;
    __syncthreads();
    {
      const int r0 = krow, r1 = krow + 16, r2 = krow + 32, r3r = krow + 48;
      *(u64*)(Kbyte + r0  * 128 + ((cf4 * 8) ^ ((r0  & 7) << 4))) = pk4(pk0);
      *(u64*)(Kbyte + r1  * 128 + ((cf4 * 8) ^ ((r1  & 7) << 4))) = pk4(pk1);
      *(u64*)(Kbyte + r2  * 128 + ((cf4 * 8) ^ ((r2  & 7) << 4))) = pk4(pk2v);
      *(u64*)(Kbyte + r3r * 128 + ((cf4 * 8) ^ ((r3r & 7) << 4))) = pk4(pk3);
      const int kvl0 = 2 * krow, kvl1 = 2 * krow + 32;
      *(u32*)(Vbyte + (d0 + 0) * 136 + kvl0 * 2) = pk2(pa0.x, pb0.x);
      *(u32*)(Vbyte + (d0 + 1) * 136 + kvl0 * 2) = pk2(pa0.y, pb0.y);
      *(u32*)(Vbyte + (d0 + 2) * 136 + kvl0 * 2) = pk2(pa0.z, pb0.z);
      *(u32*)(Vbyte + (d0 + 3) * 136 + kvl0 * 2) = pk2(pa0.w, pb0.w);
      *(u32*)(Vbyte + (d0 + 0) * 136 + kvl1 * 2) = pk2(pa1.x, pb1.x);
      *(u32*)(Vbyte + (d0 + 1) * 136 + kvl1 * 2) = pk2(pa1.y, pb1.y);
      *(u32*)(Vbyte + (d0 + 2) * 136 + kvl1 * 2) = pk2(pa1.z, pb1.z);
      *(u32*)(Vbyte + (d0 + 3) * 136 + kvl1 * 2) = pk2(pa1.w, pb1.w);
    }
    if (t + 1 < ntiles) ISSUEF(t + 1);
    asm volatile("s_waitcnt lgkmcnt(0)" ::: "memory");
    __builtin_amdgcn_s_barrier();
    asm volatile("" ::: "memory");

    f32x4 sa[4];
    for (int nn = 0; nn < 4; ++nn) {
      sa[nn] = f32x4{0.f, 0.f, 0.f, 0.f};
      const int rowk = nn * 16 + c;
      const int base = rowk * 128;
      const int swz  = (rowk & 7) << 4;
      for (int kc = 0; kc < 2; ++kc) {
        short8 kf = *(const short8*)(Kbyte + base + ((kc * 64 + 16 * g) ^ swz));
        sa[nn] = __builtin_amdgcn_mfma_f32_16x16x32_bf16(qf[kc], kf, sa[nn], 0, 0, 0);
      }
    }

    const bool diag = (t == ntiles - 1);
    float pp[4][4];
    for (int i = 0; i < 4; ++i) {
      const int qg_ = q0 + wid * 16 + 4 * g + i;
      float s0v = sa[0][i], s1v = sa[1][i], s2v = sa[2][i], s3v = sa[3][i];
      if (diag) {
        if (kv0 +  0 + c > qg_) s0v = -__builtin_inff();
        if (kv0 + 16 + c > qg_) s1v = -__builtin_inff();
        if (kv0 + 32 + c > qg_) s2v = -__builtin_inff();
        if (kv0 + 48 + c > qg_) s3v = -__builtin_inff();
      }
      float mx = fmaxf(fmaxf(s0v, s1v), fmaxf(s2v, s3v));
      mx = fmaxf(mx, __shfl_xor(mx, 1));
      mx = fmaxf(mx, __shfl_xor(mx, 2));
      mx = fmaxf(mx, __shfl_xor(mx, 4));
      mx = fmaxf(mx, __shfl_xor(mx, 8));
      const float nm = fmaxf(mrow[i], mx);
      const float al = exp2f(mrow[i] - nm);
      mrow[i] = nm;
      float p0 = exp2f(s0v - nm), p1 = exp2f(s1v - nm);
      float p2 = exp2f(s2v - nm), p3 = exp2f(s3v - nm);
      pp[0][i] = p0; pp[1][i] = p1; pp[2][i] = p2; pp[3][i] = p3;
      float ls = p0 + p1 + p2 + p3;
      ls += __shfl_xor(ls, 1);
      ls += __shfl_xor(ls, 2);
      ls += __shfl_xor(ls, 4);
      ls += __shfl_xor(ls, 8);
      lrow[i] = lrow[i] * al + ls;
      oa[0][i] *= al; oa[1][i] *= al; oa[2][i] *= al; oa[3][i] *= al;
    }

    for (int nn = 0; nn < 4; ++nn)
      for (int i = 0; i < 4; ++i)
        *(u16*)(Pbyte + ((4 * g + i) * 72 + nn * 16 + c) * 2) = f2bf(pp[nn][i]);

    for (int kc = 0; kc < 2; ++kc) {
      short8 af = *(const short8*)(Pbyte + c * 144 + kc * 64 + 16 * g);
      for (int nd = 0; nd < 4; ++nd) {
        const int d = nd * 16 + c;
        P2 pv;
        pv.a = *(const u64*)(Vbyte + d * 136 + kc * 64 + 16 * g);
        pv.b = *(const u64*)(Vbyte + d * 136 + kc * 64 + 16 * g + 8);
        short8 vf = __builtin_bit_cast(short8, pv);
        oa[nd] = __builtin_amdgcn_mfma_f32_16x16x32_bf16(af, vf, oa[nd], 0, 0, 0);
      }
    }
  }

  for (int i = 0; i < 4; ++i) {
    const float rl = 1.f / lrow[i];
    float* op = Ob + (size_t)(q0 + wid * 16 + 4 * g + i) * D_ + c;
    op[0]  = oa[0][i] * rl;
    op[16] = oa[1][i] * rl;
    op[32] = oa[2][i] * rl;
    op[48] = oa[3][i] * rl;
  }
}

extern "C" void kernel_launch(void* const* d_in, const int* in_sizes, int n_in,
                              void* d_out, int out_size, void* d_ws, size_t ws_size,
                              hipStream_t stream) {
  const float* q = (const float*)d_in[0];
  const float* k = (const float*)d_in[1];
  const float* v = (const float*)d_in[2];
  float* o = (float*)d_out;

  const size_t need = (size_t)2 * ELEMS * sizeof(u16);   // Kbf + Vbf
  if (ws_size >= need) {
    u16* kbf = (u16*)d_ws;
    u16* vbf = kbf + ELEMS;
    const int n4 = ELEMS / 4;
    convbf<<<1024, 256, 0, stream>>>(k, kbf, n4);
    convbf<<<1024, 256, 0, stream>>>(v, vbf, n4);
    fattn<<<512, 512, 0, stream>>>(q, kbf, vbf, o);
  } else {
    fattn_fb<<<1024, 256, 0, stream>>>(q, k, v, o);
  }
}